// Round 1
// baseline (884.554 us; speedup 1.0000x reference)
//
#include <hip/hip_runtime.h>
#include <cstdint>
#include <cstddef>

#define BB 64
#define TT 512
#define DD 1024
#define NTAG 64
#define SCORES_ELEMS (BB * TT * NTAG)      // 2097152
#define TAGS_OFF SCORES_ELEMS              // 2097152
#define LOSS_OFF (SCORES_ELEMS + BB * TT)  // 2130920

// ---------------- DPP wave64 reductions (rocPRIM pattern) ----------------
__device__ __forceinline__ float dpp_red_max(float v) {
  int x;
  x = __builtin_amdgcn_update_dpp(__float_as_int(v), __float_as_int(v), 0x111, 0xf, 0xf, false); // row_shr:1
  v = fmaxf(v, __int_as_float(x));
  x = __builtin_amdgcn_update_dpp(__float_as_int(v), __float_as_int(v), 0x112, 0xf, 0xf, false); // row_shr:2
  v = fmaxf(v, __int_as_float(x));
  x = __builtin_amdgcn_update_dpp(__float_as_int(v), __float_as_int(v), 0x114, 0xf, 0xf, false); // row_shr:4
  v = fmaxf(v, __int_as_float(x));
  x = __builtin_amdgcn_update_dpp(__float_as_int(v), __float_as_int(v), 0x118, 0xf, 0xf, false); // row_shr:8
  v = fmaxf(v, __int_as_float(x));
  x = __builtin_amdgcn_update_dpp(__float_as_int(v), __float_as_int(v), 0x142, 0xa, 0xf, false); // row_bcast15
  v = fmaxf(v, __int_as_float(x));
  x = __builtin_amdgcn_update_dpp(__float_as_int(v), __float_as_int(v), 0x143, 0xc, 0xf, false); // row_bcast31
  v = fmaxf(v, __int_as_float(x));
  return __int_as_float(__builtin_amdgcn_readlane(__float_as_int(v), 63));
}

__device__ __forceinline__ float dpp_red_sum(float v) {
  int x;
  x = __builtin_amdgcn_update_dpp(__float_as_int(v), __float_as_int(v), 0x111, 0xf, 0xf, false);
  v = v + __int_as_float(x);
  x = __builtin_amdgcn_update_dpp(__float_as_int(v), __float_as_int(v), 0x112, 0xf, 0xf, false);
  v = v + __int_as_float(x);
  x = __builtin_amdgcn_update_dpp(__float_as_int(v), __float_as_int(v), 0x114, 0xf, 0xf, false);
  v = v + __int_as_float(x);
  x = __builtin_amdgcn_update_dpp(__float_as_int(v), __float_as_int(v), 0x118, 0xf, 0xf, false);
  v = v + __int_as_float(x);
  x = __builtin_amdgcn_update_dpp(__float_as_int(v), __float_as_int(v), 0x142, 0xa, 0xf, false);
  v = v + __int_as_float(x);
  x = __builtin_amdgcn_update_dpp(__float_as_int(v), __float_as_int(v), 0x143, 0xc, 0xf, false);
  v = v + __int_as_float(x);
  return __int_as_float(__builtin_amdgcn_readlane(__float_as_int(v), 63));
}

// ---------------- Kernel 1: scores = (X @ W + b) * mask ----------------
// One wave handles 16 rows; lane = output column n (N=64 == wavefront).
// X row loads are wave-uniform (broadcast); W loads are coalesced; W stays in L2.
__global__ __launch_bounds__(256) void gemm_scores(
    const float* __restrict__ X, const int* __restrict__ mask,
    const float* __restrict__ W, const float* __restrict__ bias,
    float* __restrict__ scores) {
  const int lane = threadIdx.x & 63;
  const int wv = __builtin_amdgcn_readfirstlane((int)(threadIdx.x >> 6));
  const int row0 = blockIdx.x * 64 + wv * 16;
  const float bn = bias[lane];
  float acc[16];
#pragma unroll
  for (int r = 0; r < 16; ++r) acc[r] = 0.f;
  const float* Xp = X + (size_t)row0 * DD;
  for (int k = 0; k < DD; k += 4) {
    const float w0 = W[(size_t)(k + 0) * NTAG + lane];
    const float w1 = W[(size_t)(k + 1) * NTAG + lane];
    const float w2 = W[(size_t)(k + 2) * NTAG + lane];
    const float w3 = W[(size_t)(k + 3) * NTAG + lane];
#pragma unroll
    for (int r = 0; r < 16; ++r) {
      const float4 a = *reinterpret_cast<const float4*>(Xp + (size_t)r * DD + k);
      acc[r] = fmaf(a.x, w0, acc[r]);
      acc[r] = fmaf(a.y, w1, acc[r]);
      acc[r] = fmaf(a.z, w2, acc[r]);
      acc[r] = fmaf(a.w, w3, acc[r]);
    }
  }
#pragma unroll
  for (int r = 0; r < 16; ++r) {
    const int row = row0 + r;
    const float mf = (float)mask[row];
    scores[(size_t)row * NTAG + lane] = (acc[r] + bn) * mf;
  }
}

// ---------------- Kernel 2: CRF (viterbi + log-partition + gold) ----------------
// grid = 128 blocks x 64 threads. Blocks [0,64): viterbi for batch b.
// Blocks [64,128): forward log-partition + gold score for batch b.
__global__ __launch_bounds__(64) void crf_kernel(
    const float* __restrict__ scores, const int* __restrict__ mask,
    const int* __restrict__ labels, const float* __restrict__ trans,
    const float* __restrict__ startv, const float* __restrict__ endv,
    float* __restrict__ out_tags, float* __restrict__ ws_alpha,
    float* __restrict__ ws_loss) {
  const int lane = threadIdx.x;
  const int role = blockIdx.x >> 6;
  const int b = blockIdx.x & 63;
  const float* sc = scores + (size_t)b * TT * NTAG;

  if (role == 0) {
    // ---------------- Viterbi ----------------
    __shared__ __align__(16) float transT[NTAG * NTAG];  // transT[j*64+i] = trans[i][j]
    __shared__ __align__(16) float alpha_lds[NTAG];
    __shared__ int tagbuf[TT];
    float tcol[NTAG];  // tcol[i] = trans[i][lane]
#pragma unroll
    for (int i = 0; i < NTAG; ++i) {
      const float v = trans[(size_t)i * NTAG + lane];
      tcol[i] = v;
      transT[lane * NTAG + i] = v;
    }
    float valpha = startv[lane] + sc[lane];
    float emit = sc[NTAG + lane];  // t=1 emission
    float* wsA = ws_alpha + (size_t)b * (TT - 1) * NTAG;

    for (int t = 1; t < TT; ++t) {
      alpha_lds[lane] = valpha;
      wsA[(size_t)(t - 1) * NTAG + lane] = valpha;  // alpha history for backtrack
      const float emit_next = (t < TT - 1) ? sc[(size_t)(t + 1) * NTAG + lane] : 0.f;
      const int m = mask[b * TT + t];
      float best = -3.4e38f;
#pragma unroll
      for (int i = 0; i < NTAG; i += 4) {
        const float4 a4 = *reinterpret_cast<const float4*>(&alpha_lds[i]);
        const float c0 = a4.x + tcol[i + 0];
        const float c1 = a4.y + tcol[i + 1];
        const float c2 = a4.z + tcol[i + 2];
        const float c3 = a4.w + tcol[i + 3];
        best = fmaxf(best, fmaxf(fmaxf(c0, c1), fmaxf(c2, c3)));
      }
      const float cand = best + emit;
      valpha = m ? cand : valpha;
      emit = emit_next;
    }

    // last tag = argmax_j (alpha + end), first index on ties (jnp.argmax)
    const float fin = valpha + endv[lane];
    const float mx = dpp_red_max(fin);
    unsigned long long bal = __ballot(fin == mx);
    int jcur = (int)__builtin_ctzll(bal);
    if (lane == 0) tagbuf[TT - 1] = jcur;

    // backtrack: recompute argmax along the path only; bit-identical adds ->
    // exact max match -> ballot+ctz reproduces first-occurrence argmax.
    float a_cur = wsA[(size_t)(TT - 2) * NTAG + lane];
    for (int s = TT - 2; s >= 0; --s) {
      const float a_next = (s > 0) ? wsA[(size_t)(s - 1) * NTAG + lane] : 0.f;
      const int m = mask[b * TT + s + 1];
      if (m) {
        const float c = a_cur + transT[jcur * NTAG + lane];
        const float cmx = dpp_red_max(c);
        const unsigned long long bmask = __ballot(c == cmx);
        jcur = (int)__builtin_ctzll(bmask);
      }
      if (lane == 0) tagbuf[s] = jcur;
      a_cur = a_next;
    }

    // write tags (as float; final * mask)
    for (int t = lane; t < TT; t += 64) {
      const int m = mask[b * TT + t];
      out_tags[b * TT + t] = (float)(m ? tagbuf[t] : 0);
    }
  } else {
    // ---------------- log-partition + gold ----------------
    __shared__ __align__(16) float e_lds[NTAG];
    float ecol[NTAG];  // exp(trans[i][lane])
#pragma unroll
    for (int i = 0; i < NTAG; ++i) ecol[i] = expf(trans[(size_t)i * NTAG + lane]);
    float lalpha = startv[lane] + sc[lane];
    float emit = sc[NTAG + lane];
    for (int t = 1; t < TT; ++t) {
      const float emit_next = (t < TT - 1) ? sc[(size_t)(t + 1) * NTAG + lane] : 0.f;
      const int m = mask[b * TT + t];
      const float M = dpp_red_max(lalpha);
      const float e = expf(lalpha - M);
      e_lds[lane] = e;
      float s0 = 0.f, s1 = 0.f, s2 = 0.f, s3 = 0.f;
#pragma unroll
      for (int i = 0; i < NTAG; i += 4) {
        const float4 e4 = *reinterpret_cast<const float4*>(&e_lds[i]);
        s0 = fmaf(e4.x, ecol[i + 0], s0);
        s1 = fmaf(e4.y, ecol[i + 1], s1);
        s2 = fmaf(e4.z, ecol[i + 2], s2);
        s3 = fmaf(e4.w, ecol[i + 3], s3);
      }
      const float ssum = (s0 + s1) + (s2 + s3);
      const float cand = logf(ssum) + M + emit;
      lalpha = m ? cand : lalpha;
      emit = emit_next;
    }
    // log_z = logsumexp(lalpha + end)
    const float fv = lalpha + endv[lane];
    const float M2 = dpp_red_max(fv);
    const float ex = expf(fv - M2);
    const float sSum = dpp_red_sum(ex);
    const float log_z = logf(sSum) + M2;

    // gold joint score
    float g = 0.f;
    float msumf = 0.f;
    for (int t = lane; t < TT; t += 64) {
      const int lab = labels[b * TT + t];
      const int mi = mask[b * TT + t];
      const float mf = (float)mi;
      msumf += mf;
      g += sc[(size_t)t * NTAG + lab] * mf;
      if (t >= 1) {
        const int labp = labels[b * TT + t - 1];
        g += trans[(size_t)labp * NTAG + lab] * mf;
      }
    }
    g = dpp_red_sum(g);
    const float msum = dpp_red_sum(msumf);
    const int last_idx = (int)msum - 1;
    g += startv[labels[b * TT]] + endv[labels[b * TT + last_idx]];
    if (lane == 0) ws_loss[b] = log_z - g;
  }
}

// ---------------- Kernel 3: loss = mean(log_z - gold) ----------------
__global__ __launch_bounds__(64) void loss_mean(const float* __restrict__ ws_loss,
                                                float* __restrict__ out) {
  const float v = ws_loss[threadIdx.x];
  const float s = dpp_red_sum(v);
  if (threadIdx.x == 0) out[0] = s * (1.0f / 64.0f);
}

extern "C" void kernel_launch(void* const* d_in, const int* in_sizes, int n_in,
                              void* d_out, int out_size, void* d_ws, size_t ws_size,
                              hipStream_t stream) {
  const float* X = (const float*)d_in[0];
  const int* mask = (const int*)d_in[1];
  const int* labels = (const int*)d_in[2];
  const float* W = (const float*)d_in[3];
  const float* bias = (const float*)d_in[4];
  const float* trans = (const float*)d_in[5];
  const float* startv = (const float*)d_in[6];
  const float* endv = (const float*)d_in[7];

  float* out = (float*)d_out;
  float* scores = out;
  float* out_tags = out + TAGS_OFF;
  float* out_loss = out + LOSS_OFF;

  float* ws_alpha = (float*)d_ws;                            // 64*511*64 floats
  float* ws_loss = ws_alpha + (size_t)BB * (TT - 1) * NTAG;  // 64 floats

  gemm_scores<<<512, 256, 0, stream>>>(X, mask, W, bias, scores);
  crf_kernel<<<128, 64, 0, stream>>>(scores, mask, labels, trans, startv, endv,
                                     out_tags, ws_alpha, ws_loss);
  loss_mean<<<1, 64, 0, stream>>>(ws_loss, out_loss);
}

// Round 2
// 634.376 us; speedup vs baseline: 1.3944x; 1.3944x over previous
//
#include <hip/hip_runtime.h>
#include <cstdint>
#include <cstddef>

#define BB 64
#define TT 512
#define DD 1024
#define NTAG 64
#define SCORES_ELEMS (BB * TT * NTAG)      // 2097152
#define TAGS_OFF SCORES_ELEMS              // 2097152
#define LOSS_OFF (SCORES_ELEMS + BB * TT)  // 2130920

// ---------------- DPP wave64 reductions ----------------
__device__ __forceinline__ float dpp_red_max(float v) {
  int x;
  x = __builtin_amdgcn_update_dpp(__float_as_int(v), __float_as_int(v), 0x111, 0xf, 0xf, false);
  v = fmaxf(v, __int_as_float(x));
  x = __builtin_amdgcn_update_dpp(__float_as_int(v), __float_as_int(v), 0x112, 0xf, 0xf, false);
  v = fmaxf(v, __int_as_float(x));
  x = __builtin_amdgcn_update_dpp(__float_as_int(v), __float_as_int(v), 0x114, 0xf, 0xf, false);
  v = fmaxf(v, __int_as_float(x));
  x = __builtin_amdgcn_update_dpp(__float_as_int(v), __float_as_int(v), 0x118, 0xf, 0xf, false);
  v = fmaxf(v, __int_as_float(x));
  x = __builtin_amdgcn_update_dpp(__float_as_int(v), __float_as_int(v), 0x142, 0xa, 0xf, false);
  v = fmaxf(v, __int_as_float(x));
  x = __builtin_amdgcn_update_dpp(__float_as_int(v), __float_as_int(v), 0x143, 0xc, 0xf, false);
  v = fmaxf(v, __int_as_float(x));
  return __int_as_float(__builtin_amdgcn_readlane(__float_as_int(v), 63));
}

__device__ __forceinline__ float dpp_red_sum(float v) {
  int x;
  x = __builtin_amdgcn_update_dpp(__float_as_int(v), __float_as_int(v), 0x111, 0xf, 0xf, false);
  v = v + __int_as_float(x);
  x = __builtin_amdgcn_update_dpp(__float_as_int(v), __float_as_int(v), 0x112, 0xf, 0xf, false);
  v = v + __int_as_float(x);
  x = __builtin_amdgcn_update_dpp(__float_as_int(v), __float_as_int(v), 0x114, 0xf, 0xf, false);
  v = v + __int_as_float(x);
  x = __builtin_amdgcn_update_dpp(__float_as_int(v), __float_as_int(v), 0x118, 0xf, 0xf, false);
  v = v + __int_as_float(x);
  x = __builtin_amdgcn_update_dpp(__float_as_int(v), __float_as_int(v), 0x142, 0xa, 0xf, false);
  v = v + __int_as_float(x);
  x = __builtin_amdgcn_update_dpp(__float_as_int(v), __float_as_int(v), 0x143, 0xc, 0xf, false);
  v = v + __int_as_float(x);
  return __int_as_float(__builtin_amdgcn_readlane(__float_as_int(v), 63));
}

// ---------------- Kernel 1: scores = (X @ W + b) * mask ----------------
// 1024 blocks x 256 threads; 32 rows/block, 8 rows/wave, lane = column j.
// X staged in LDS via coalesced VECTOR loads (avoids scalar-cache streaming);
// broadcasts come from uniform ds_read_b128.
#define ROWS_PB 32
#define KC 64
__global__ __launch_bounds__(256) void gemm_scores(
    const float* __restrict__ X, const int* __restrict__ mask,
    const float* __restrict__ W, const float* __restrict__ bias,
    float* __restrict__ scores) {
  __shared__ __align__(16) float xt[ROWS_PB][KC + 4];  // stride 68 floats = 272B (16B aligned)
  const int tid = threadIdx.x;
  const int lane = tid & 63;
  const int wv = tid >> 6;
  const int row0 = blockIdx.x * ROWS_PB;
  const float bn = bias[lane];
  float acc[8];
#pragma unroll
  for (int r = 0; r < 8; ++r) acc[r] = 0.f;

  const int kpart = (tid & 15) << 2;  // 0..60 step 4
  const int rstage = tid >> 4;        // 0..15

  for (int kc = 0; kc < DD; kc += KC) {
    __syncthreads();  // previous chunk's readers done
#pragma unroll
    for (int p = 0; p < 2; ++p) {
      const int r = p * 16 + rstage;
      const float4 v = *reinterpret_cast<const float4*>(
          X + (size_t)(row0 + r) * DD + kc + kpart);
      *reinterpret_cast<float4*>(&xt[r][kpart]) = v;
    }
    __syncthreads();
    const float* Wp = W + (size_t)kc * NTAG + lane;
    const int rbase = wv * 8;
#pragma unroll
    for (int kk = 0; kk < KC; kk += 4) {
      const float w0 = Wp[(size_t)(kk + 0) * NTAG];
      const float w1 = Wp[(size_t)(kk + 1) * NTAG];
      const float w2 = Wp[(size_t)(kk + 2) * NTAG];
      const float w3 = Wp[(size_t)(kk + 3) * NTAG];
#pragma unroll
      for (int r = 0; r < 8; ++r) {
        const float4 a = *reinterpret_cast<const float4*>(&xt[rbase + r][kk]);
        acc[r] = fmaf(a.x, w0, acc[r]);
        acc[r] = fmaf(a.y, w1, acc[r]);
        acc[r] = fmaf(a.z, w2, acc[r]);
        acc[r] = fmaf(a.w, w3, acc[r]);
      }
    }
  }
  const int rbase = wv * 8;
#pragma unroll
  for (int r = 0; r < 8; ++r) {
    const int row = row0 + rbase + r;
    const float mf = (float)mask[row];
    scores[(size_t)row * NTAG + lane] = (acc[r] + bn) * mf;
  }
}

// ---------------- Kernel 2: CRF (viterbi + log-partition + gold) ----------------
__global__ __launch_bounds__(64) void crf_kernel(
    const float* __restrict__ scores, const int* __restrict__ mask,
    const int* __restrict__ labels, const float* __restrict__ trans,
    const float* __restrict__ startv, const float* __restrict__ endv,
    float* __restrict__ out_tags, float* __restrict__ ws_alpha,
    float* __restrict__ ws_loss) {
  const int lane = threadIdx.x;
  const int role = blockIdx.x >> 6;
  const int b = blockIdx.x & 63;
  const float* sc = scores + (size_t)b * TT * NTAG;
  const int* maskb = mask + b * TT;

  if (role == 0) {
    // ---------------- Viterbi ----------------
    __shared__ __align__(16) float transT[NTAG * NTAG];
    __shared__ __align__(16) float alpha_lds[NTAG];
    __shared__ int tagbuf[TT];
    float tcol[NTAG];  // tcol[i] = trans[i][lane]
#pragma unroll
    for (int i = 0; i < NTAG; ++i) {
      const float v = trans[(size_t)i * NTAG + lane];
      tcol[i] = v;
      transT[lane * NTAG + i] = v;
    }
    float valpha = startv[lane] + sc[lane];
    float* wsA = ws_alpha + (size_t)b * (TT - 1) * NTAG;

    // rotating prefetch pipelines (depth 4): emissions + mask
    float e0 = sc[1 * NTAG + lane], e1 = sc[2 * NTAG + lane];
    float e2 = sc[3 * NTAG + lane], e3 = sc[4 * NTAG + lane];
    int k0 = maskb[1], k1 = maskb[2], k2 = maskb[3], k3 = maskb[4];

    for (int t = 1; t < TT; ++t) {
      alpha_lds[lane] = valpha;
      wsA[(size_t)(t - 1) * NTAG + lane] = valpha;
      const float emit = e0;
      const int m = k0;
      const int tp = (t + 4 < TT) ? (t + 4) : (TT - 1);
      e0 = e1; e1 = e2; e2 = e3;
      e3 = sc[(size_t)tp * NTAG + lane];
      k0 = k1; k1 = k2; k2 = k3;
      k3 = maskb[tp];

      float best = -3.4e38f;
#pragma unroll
      for (int i = 0; i < NTAG; i += 4) {
        const float4 a4 = *reinterpret_cast<const float4*>(&alpha_lds[i]);
        const float c0 = a4.x + tcol[i + 0];
        const float c1 = a4.y + tcol[i + 1];
        const float c2 = a4.z + tcol[i + 2];
        const float c3 = a4.w + tcol[i + 3];
        best = fmaxf(best, fmaxf(fmaxf(c0, c1), fmaxf(c2, c3)));
      }
      valpha = m ? (best + emit) : valpha;
    }

    const float fin = valpha + endv[lane];
    const float mx = dpp_red_max(fin);
    int jcur = (int)__builtin_ctzll(__ballot(fin == mx));
    if (lane == 0) tagbuf[TT - 1] = jcur;

    // backtrack (recompute argmax along path; adds bit-identical to fwd)
    float aw0 = wsA[(size_t)(TT - 2) * NTAG + lane];  // alpha_510
    float aw1 = wsA[(size_t)(TT - 3) * NTAG + lane];  // alpha_509
    int mk0 = maskb[TT - 1], mk1 = maskb[TT - 2];
    for (int s = TT - 2; s >= 0; --s) {
      const float a_cur = aw0;
      aw0 = aw1;
      const int i2 = (s >= 2) ? (s - 2) : 0;
      aw1 = wsA[(size_t)i2 * NTAG + lane];
      const int m = mk0;
      mk0 = mk1;
      mk1 = maskb[(s >= 1) ? (s - 1) : 0];
      if (m) {
        const float c = a_cur + transT[jcur * NTAG + lane];
        const float cmx = dpp_red_max(c);
        jcur = (int)__builtin_ctzll(__ballot(c == cmx));
      }
      if (lane == 0) tagbuf[s] = jcur;
    }

    for (int t = lane; t < TT; t += 64) {
      const int m = maskb[t];
      out_tags[b * TT + t] = (float)(m ? tagbuf[t] : 0);
    }
  } else {
    // ---------------- log-partition + gold ----------------
    __shared__ __align__(16) float e_lds[NTAG];
    float ecol[NTAG];
#pragma unroll
    for (int i = 0; i < NTAG; ++i) ecol[i] = expf(trans[(size_t)i * NTAG + lane]);
    float lalpha = startv[lane] + sc[lane];

    float e0 = sc[1 * NTAG + lane], e1 = sc[2 * NTAG + lane];
    float e2 = sc[3 * NTAG + lane], e3 = sc[4 * NTAG + lane];
    int k0 = maskb[1], k1 = maskb[2], k2 = maskb[3], k3 = maskb[4];

    for (int t = 1; t < TT; ++t) {
      const float emit = e0;
      const int m = k0;
      const int tp = (t + 4 < TT) ? (t + 4) : (TT - 1);
      e0 = e1; e1 = e2; e2 = e3;
      e3 = sc[(size_t)tp * NTAG + lane];
      k0 = k1; k1 = k2; k2 = k3;
      k3 = maskb[tp];

      // stabilizer: alpha[0] (exact logsumexp identity; spread <= ~10 so safe)
      const float M = __int_as_float(__builtin_amdgcn_readlane(__float_as_int(lalpha), 0));
      e_lds[lane] = expf(lalpha - M);
      float s0 = 0.f, s1 = 0.f, s2 = 0.f, s3 = 0.f;
#pragma unroll
      for (int i = 0; i < NTAG; i += 4) {
        const float4 e4 = *reinterpret_cast<const float4*>(&e_lds[i]);
        s0 = fmaf(e4.x, ecol[i + 0], s0);
        s1 = fmaf(e4.y, ecol[i + 1], s1);
        s2 = fmaf(e4.z, ecol[i + 2], s2);
        s3 = fmaf(e4.w, ecol[i + 3], s3);
      }
      const float ssum = (s0 + s1) + (s2 + s3);
      lalpha = m ? (logf(ssum) + M + emit) : lalpha;
    }
    const float fv = lalpha + endv[lane];
    const float M2 = dpp_red_max(fv);
    const float sSum = dpp_red_sum(expf(fv - M2));
    const float log_z = logf(sSum) + M2;

    float g = 0.f, msumf = 0.f;
    for (int t = lane; t < TT; t += 64) {
      const int lab = labels[b * TT + t];
      const float mf = (float)maskb[t];
      msumf += mf;
      g += sc[(size_t)t * NTAG + lab] * mf;
      if (t >= 1) {
        const int labp = labels[b * TT + t - 1];
        g += trans[(size_t)labp * NTAG + lab] * mf;
      }
    }
    g = dpp_red_sum(g);
    const float msum = dpp_red_sum(msumf);
    const int last_idx = (int)msum - 1;
    g += startv[labels[b * TT]] + endv[labels[b * TT + last_idx]];
    if (lane == 0) ws_loss[b] = log_z - g;
  }
}

// ---------------- Kernel 3: loss = mean(log_z - gold) ----------------
__global__ __launch_bounds__(64) void loss_mean(const float* __restrict__ ws_loss,
                                                float* __restrict__ out) {
  const float v = ws_loss[threadIdx.x];
  const float s = dpp_red_sum(v);
  if (threadIdx.x == 0) out[0] = s * (1.0f / 64.0f);
}

extern "C" void kernel_launch(void* const* d_in, const int* in_sizes, int n_in,
                              void* d_out, int out_size, void* d_ws, size_t ws_size,
                              hipStream_t stream) {
  const float* X = (const float*)d_in[0];
  const int* mask = (const int*)d_in[1];
  const int* labels = (const int*)d_in[2];
  const float* W = (const float*)d_in[3];
  const float* bias = (const float*)d_in[4];
  const float* trans = (const float*)d_in[5];
  const float* startv = (const float*)d_in[6];
  const float* endv = (const float*)d_in[7];

  float* out = (float*)d_out;
  float* scores = out;
  float* out_tags = out + TAGS_OFF;
  float* out_loss = out + LOSS_OFF;

  float* ws_alpha = (float*)d_ws;
  float* ws_loss = ws_alpha + (size_t)BB * (TT - 1) * NTAG;

  gemm_scores<<<DD, 256, 0, stream>>>(X, mask, W, bias, scores);  // 1024 blocks
  crf_kernel<<<128, 64, 0, stream>>>(scores, mask, labels, trans, startv, endv,
                                     out_tags, ws_alpha, ws_loss);
  loss_mean<<<1, 64, 0, stream>>>(ws_loss, out_loss);
}